// Round 1
// baseline (187.468 us; speedup 1.0000x reference)
//
#include <hip/hip_runtime.h>
#include <hip/hip_bf16.h>

// InfoNCE loss, fused flash-style:
//   loss = (1/B) * sum_i [ log(sum_j exp(Q_i . D_j / T)) - Q_i . D_{2i} / T ]
// Logits bounded (|logit| < ~10) -> skip max-subtraction; per-row sum-exp is
// a plain commutative accumulation (atomicAdd merge across doc-chunks).
// GEMM in bf16 MFMA (threshold 0.205 on loss ~10.25; bf16 logit noise ~5e-3).
//
// ws layout (needs ~24.1 MB):
//   [0)               Qbf  B*K bf16      (8 MB)
//   [B*K*2)           Dbf  N*K bf16      (16 MB)
//   [+N*K*2)          rowsum B f32       (16 KB)   zeroed by cvt kernel
//   [+B*4)            pos    B f32       (16 KB)

#define BM 128
#define BN 128
#define BK 32
#define CHUNK 512
#define TEMP_INV 50.0f

typedef __bf16 bf16x8 __attribute__((ext_vector_type(8)));
typedef float f32x4 __attribute__((ext_vector_type(4)));

__device__ inline unsigned short f2bf(float f) {
    union { float f; unsigned int u; } x; x.f = f;
    unsigned int r = x.u + 0x7fffu + ((x.u >> 16) & 1u);   // RNE
    return (unsigned short)(r >> 16);
}

// ---------------- convert fp32 -> bf16, zero rowsum ----------------
__global__ void cvt_kernel(const float* __restrict__ Q, const float* __restrict__ Dm,
                           unsigned short* __restrict__ Qb, unsigned short* __restrict__ Db,
                           float* __restrict__ rowsum, int qElems, int dElems, int B) {
    int gid = blockIdx.x * blockDim.x + threadIdx.x;
    if (gid < B) rowsum[gid] = 0.0f;
    int idx = gid * 4;
    if (idx < qElems) {
        float4 v = *(const float4*)(Q + idx);
        ushort4 o;
        o.x = f2bf(v.x); o.y = f2bf(v.y); o.z = f2bf(v.z); o.w = f2bf(v.w);
        *(ushort4*)(Qb + idx) = o;
    } else if (idx < qElems + dElems) {
        int d = idx - qElems;
        float4 v = *(const float4*)(Dm + d);
        ushort4 o;
        o.x = f2bf(v.x); o.y = f2bf(v.y); o.z = f2bf(v.z); o.w = f2bf(v.w);
        *(ushort4*)(Db + d) = o;
    }
}

// ---------------- fused bf16 GEMM + row sum-exp ----------------
// grid: (B/BM, N/CHUNK); block: 256 (4 waves). m97-style 128x128 tile,
// BK=32, global_load_lds width=16 staging, 16x16x32 bf16 MFMA.
__global__ __launch_bounds__(256, 2) void gemm_expsum_kernel(
        const unsigned short* __restrict__ Qb, const unsigned short* __restrict__ Db,
        float* __restrict__ rowsum, int K) {
    __shared__ unsigned short Qs[BM * BK];   // [row][k] row-major, 64 B/row
    __shared__ unsigned short Ds[BN * BK];

    const int qbase = blockIdx.x * BM;
    const int dbase = blockIdx.y * CHUNK;
    const int tid   = threadIdx.x;
    const int wave  = tid >> 6;
    const int lane  = tid & 63;
    const int wrow  = (wave >> 1) * 64;   // wave quadrant in 128x128 tile
    const int wcol  = (wave & 1) * 64;
    const int lquad = lane >> 4;
    const int lm    = lane & 15;

    // staging: chunk c = wave*2+q covers LDS rows c*16..c*16+15 (1 KB each),
    // lane l -> row c*16 + l/4, 16B segment (l&3). Per-lane LDS ptr is
    // uniform-base + lane*16 (global_load_lds requirement).
    const int srow0 = wave * 32 + (lane >> 2);
    const int sseg  = (lane & 3) * 8;

    float rowAcc[16];
#pragma unroll
    for (int t = 0; t < 16; ++t) rowAcc[t] = 0.0f;

    const unsigned short* Qtile = Qb + (size_t)qbase * K;

    for (int dt = 0; dt < CHUNK / BN; ++dt) {
        f32x4 acc[16];
#pragma unroll
        for (int t = 0; t < 16; ++t) acc[t] = (f32x4){0.f, 0.f, 0.f, 0.f};
        const unsigned short* Dtile = Db + (size_t)(dbase + dt * BN) * K;

        for (int k0 = 0; k0 < K; k0 += BK) {
#pragma unroll
            for (int q = 0; q < 2; ++q) {
                int row = srow0 + q * 16;
                const unsigned short* g1 = Qtile + (size_t)row * K + k0 + sseg;
                unsigned short* l1 = Qs + row * BK + sseg;
                __builtin_amdgcn_global_load_lds(
                    (const __attribute__((address_space(1))) void*)g1,
                    (__attribute__((address_space(3))) void*)l1, 16, 0, 0);
                const unsigned short* g2 = Dtile + (size_t)row * K + k0 + sseg;
                unsigned short* l2 = Ds + row * BK + sseg;
                __builtin_amdgcn_global_load_lds(
                    (const __attribute__((address_space(1))) void*)g2,
                    (__attribute__((address_space(3))) void*)l2, 16, 0, 0);
            }
            __syncthreads();   // drains vmcnt -> LDS tiles ready

            bf16x8 af[4], bfv[4];
#pragma unroll
            for (int i = 0; i < 4; ++i)
                af[i] = *(const bf16x8*)(Qs + (wrow + 16 * i + lm) * BK + lquad * 8);
#pragma unroll
            for (int j = 0; j < 4; ++j)
                bfv[j] = *(const bf16x8*)(Ds + (wcol + 16 * j + lm) * BK + lquad * 8);
#pragma unroll
            for (int i = 0; i < 4; ++i)
#pragma unroll
                for (int j = 0; j < 4; ++j)
                    acc[i * 4 + j] = __builtin_amdgcn_mfma_f32_16x16x32_bf16(
                        af[i], bfv[j], acc[i * 4 + j], 0, 0, 0);
            __syncthreads();   // all waves done reading before next stage
        }

        // epilogue: exp and accumulate per-row partial sums.
        // C layout: col = lane&15, row = (lane>>4)*4 + reg  [m89/m91]
#pragma unroll
        for (int i = 0; i < 4; ++i)
#pragma unroll
            for (int r = 0; r < 4; ++r) {
                float e = 0.0f;
#pragma unroll
                for (int j = 0; j < 4; ++j)
                    e += __expf(acc[i * 4 + j][r] * TEMP_INV);
                rowAcc[i * 4 + r] += e;
            }
    }

    // butterfly across the 16 column-lanes (lane bits 0..3)
#pragma unroll
    for (int t = 0; t < 16; ++t) {
        float v = rowAcc[t];
        v += __shfl_xor(v, 1);
        v += __shfl_xor(v, 2);
        v += __shfl_xor(v, 4);
        v += __shfl_xor(v, 8);
        rowAcc[t] = v;
    }
    if (lm == 0) {
#pragma unroll
        for (int i = 0; i < 4; ++i)
#pragma unroll
            for (int r = 0; r < 4; ++r)
                atomicAdd(&rowsum[qbase + wrow + 16 * i + 4 * lquad + r],
                          rowAcc[i * 4 + r]);
    }
}

// ---------------- exact fp32 positive logit: pos_i = (Q_i . D_{i*dper}) / T ----
__global__ void pos_kernel(const float* __restrict__ Q, const float* __restrict__ Dm,
                           const int* __restrict__ dper, float* __restrict__ pos,
                           int B, int K) {
    int gwave = (blockIdx.x * blockDim.x + threadIdx.x) >> 6;
    int lane  = threadIdx.x & 63;
    if (gwave >= B) return;
    int dp = dper[0];
    const float* q = Q + (size_t)gwave * K;
    const float* d = Dm + (size_t)gwave * dp * K;
    float s = 0.0f;
    for (int k = lane * 4; k < K; k += 64 * 4) {
        float4 a = *(const float4*)(q + k);
        float4 b = *(const float4*)(d + k);
        s += a.x * b.x + a.y * b.y + a.z * b.z + a.w * b.w;
    }
    s += __shfl_xor(s, 32);
    s += __shfl_xor(s, 16);
    s += __shfl_xor(s, 8);
    s += __shfl_xor(s, 4);
    s += __shfl_xor(s, 2);
    s += __shfl_xor(s, 1);
    if (lane == 0) pos[gwave] = s * TEMP_INV;
}

// ---------------- final: loss = sum(log(rowsum) - pos)/B ----------------
__global__ void final_kernel(const float* __restrict__ rowsum,
                             const float* __restrict__ pos,
                             float* __restrict__ out, int B) {
    __shared__ float red[16];
    int tid = threadIdx.x;   // 1024 threads
    float s = 0.0f;
    for (int i = tid; i < B; i += blockDim.x)
        s += __logf(rowsum[i]) - pos[i];
    s += __shfl_xor(s, 32);
    s += __shfl_xor(s, 16);
    s += __shfl_xor(s, 8);
    s += __shfl_xor(s, 4);
    s += __shfl_xor(s, 2);
    s += __shfl_xor(s, 1);
    int w = tid >> 6, l = tid & 63;
    if (l == 0) red[w] = s;
    __syncthreads();
    if (tid == 0) {
        float t = 0.0f;
        int nw = blockDim.x >> 6;
        for (int i = 0; i < nw; ++i) t += red[i];
        out[0] = t / (float)B;
    }
}

extern "C" void kernel_launch(void* const* d_in, const int* in_sizes, int n_in,
                              void* d_out, int out_size, void* d_ws, size_t ws_size,
                              hipStream_t stream) {
    const float* Q   = (const float*)d_in[0];
    const float* Dm  = (const float*)d_in[1];
    const int* dper  = (const int*)d_in[2];
    float* out = (float*)d_out;

    const int DIM  = 1024;
    const int B    = in_sizes[0] / DIM;   // 4096
    const int Ntot = in_sizes[1] / DIM;   // 8192

    unsigned short* Qb = (unsigned short*)d_ws;
    unsigned short* Db = Qb + (size_t)B * DIM;
    float* rowsum = (float*)(Db + (size_t)Ntot * DIM);
    float* pos = rowsum + B;

    int totalElems = (B + Ntot) * DIM;
    int cvtThreads = totalElems / 4;
    cvt_kernel<<<(cvtThreads + 255) / 256, 256, 0, stream>>>(
        Q, Dm, Qb, Db, rowsum, B * DIM, Ntot * DIM, B);

    dim3 grid(B / BM, Ntot / CHUNK);
    gemm_expsum_kernel<<<grid, 256, 0, stream>>>(Qb, Db, rowsum, DIM);

    pos_kernel<<<B / 4, 256, 0, stream>>>(Q, Dm, dper, pos, B, DIM);

    final_kernel<<<1, 1024, 0, stream>>>(rowsum, pos, out, B);
}

// Round 2
// 171.558 us; speedup vs baseline: 1.0927x; 1.0927x over previous
//
#include <hip/hip_runtime.h>
#include <hip/hip_bf16.h>

// InfoNCE loss, fused flash-style:
//   loss = (1/B) * sum_i [ log(sum_j exp(Q_i . D_j / T)) - Q_i . D_{pos} / T ]
// Logits bounded (|logit| < ~10) -> no max-subtraction; per-row sum-exp is
// commutative -> atomicAdd merge across column-blocks.
// GEMM in bf16 MFMA; pos-logit exact fp32 (fused into cvt kernel).
//
// R2 changes vs R1:
//  - CHUNK=128 (no dt loop): grid 32x64=2048 blocks -> ~7 blocks/CU occupancy
//  - swizzled global->LDS staging (p = (s + (row>>2))&3): kills the 4-way
//    bank-group conflicts on ds_read_b128 (8.4M conflict cycles -> ~0)
//  - pos-logit fused into cvt kernel (one block per Q row) -> -1 dispatch,
//    -16MB fp32 traffic
//
// ws layout (~24.1 MB):
//   [0)        Qbf  B*K bf16    (8 MB)
//   [B*K*2)    Dbf  N*K bf16    (16 MB)
//   [+N*K*2)   rowsum B f32     (16 KB)  zeroed by cvt kernel
//   [+B*4)     pos    B f32     (16 KB)

#define BM 128
#define BN 128
#define BK 32
#define TEMP_INV 50.0f

typedef __bf16 bf16x8 __attribute__((ext_vector_type(8)));
typedef float f32x4 __attribute__((ext_vector_type(4)));

__device__ inline unsigned short f2bf(float f) {
    union { float f; unsigned int u; } x; x.f = f;
    unsigned int r = x.u + 0x7fffu + ((x.u >> 16) & 1u);   // RNE
    return (unsigned short)(r >> 16);
}

// ---------------- convert fp32 -> bf16, zero rowsum, fused exact pos-logit ---
// Block b < B: handles Q row b (256 thr x 4 elem = 1024 = K), converts it,
//   and computes pos[b] = (Q_b . D_{b*dper}) / T in fp32.
// Block b >= B: converts D row (b - B).
__global__ void cvt_pos_kernel(const float* __restrict__ Q, const float* __restrict__ Dm,
                               const int* __restrict__ dper,
                               unsigned short* __restrict__ Qb, unsigned short* __restrict__ Db,
                               float* __restrict__ rowsum, float* __restrict__ pos,
                               int B, int K) {
    __shared__ float red[4];
    const int b = blockIdx.x;
    const int t = threadIdx.x;
    const int idx = t * 4;
    if (b < B) {
        const float* q = Q + (size_t)b * K;
        float4 v = *(const float4*)(q + idx);
        ushort4 o;
        o.x = f2bf(v.x); o.y = f2bf(v.y); o.z = f2bf(v.z); o.w = f2bf(v.w);
        *(ushort4*)(Qb + (size_t)b * K + idx) = o;
        int dp = dper[0];
        float4 d = *(const float4*)(Dm + (size_t)b * dp * K + idx);
        float s = v.x * d.x + v.y * d.y + v.z * d.z + v.w * d.w;
        s += __shfl_xor(s, 32);
        s += __shfl_xor(s, 16);
        s += __shfl_xor(s, 8);
        s += __shfl_xor(s, 4);
        s += __shfl_xor(s, 2);
        s += __shfl_xor(s, 1);
        int w = t >> 6, l = t & 63;
        if (l == 0) red[w] = s;
        __syncthreads();
        if (t == 0) {
            pos[b] = (red[0] + red[1] + red[2] + red[3]) * TEMP_INV;
            rowsum[b] = 0.0f;
        }
    } else {
        const int r = b - B;
        float4 v = *(const float4*)(Dm + (size_t)r * K + idx);
        ushort4 o;
        o.x = f2bf(v.x); o.y = f2bf(v.y); o.z = f2bf(v.z); o.w = f2bf(v.w);
        *(ushort4*)(Db + (size_t)r * K + idx) = o;
    }
}

// ---------------- fused bf16 GEMM + row sum-exp ----------------
// grid: (B/BM, N/BN); block: 256 (4 waves). m97-style 128x128 tile, BK=32,
// global_load_lds width=16 staging with source-swizzle, 16x16x32 bf16 MFMA.
//
// LDS layout swizzle: row stride 64B (=16 banks) makes the natural layout
// 4-way bank-group-conflicted for quarter-wave b128 reads. We place logical
// 16B segment s of row r at physical segment p = (s + (r>>2)) & 3. Since the
// global_load_lds LDS destination is lane-linear (base + lane*16), we instead
// permute the GLOBAL source per lane: s = ((lane&3) - (lane>>4)) & 3.
// Readers use p = (lquad + (lm>>2)) & 3. Bank group per quarter-wave covers
// each 4-bank group exactly twice -> 2-way -> free (m136).
__global__ __launch_bounds__(256, 2) void gemm_expsum_kernel(
        const unsigned short* __restrict__ Qb, const unsigned short* __restrict__ Db,
        float* __restrict__ rowsum, int K) {
    __shared__ unsigned short Qs[BM * BK];   // [row][k] 64 B/row, seg-swizzled
    __shared__ unsigned short Ds[BN * BK];

    const int qbase = blockIdx.x * BM;
    const int dbase = blockIdx.y * BN;
    const int tid   = threadIdx.x;
    const int wave  = tid >> 6;
    const int lane  = tid & 63;
    const int wrow  = (wave >> 1) * 64;   // wave quadrant in 128x128 tile
    const int wcol  = (wave & 1) * 64;
    const int lquad = lane >> 4;
    const int lm    = lane & 15;

    // staging: chunk c = wave*2+q covers tile rows 16c..16c+15 (1 KB each).
    // lane l -> LDS dest (row 16c + l/4, phys seg l&3) = base + l*16.
    // swizzled global source: logical seg s = ((l&3) - (l>>4)) & 3.
    const int crow = lane >> 2;                                  // row in chunk
    const int sseg = (((lane & 3) - (lane >> 4)) & 3) * 8;       // elems
    // reader physical segment (elems): p = (lquad + (lm>>2)) & 3
    const int pseg = ((lquad + (lm >> 2)) & 3) * 8;

    const unsigned short* Qtile = Qb + (size_t)qbase * K;
    const unsigned short* Dtile = Db + (size_t)dbase * K;

    f32x4 acc[16];
#pragma unroll
    for (int t = 0; t < 16; ++t) acc[t] = (f32x4){0.f, 0.f, 0.f, 0.f};

    for (int k0 = 0; k0 < K; k0 += BK) {
#pragma unroll
        for (int q = 0; q < 2; ++q) {
            const int c = wave * 2 + q;
            const int row = c * 16 + crow;
            const unsigned short* g1 = Qtile + (size_t)row * K + k0 + sseg;
            unsigned short* l1 = Qs + c * 512 + lane * 8;
            __builtin_amdgcn_global_load_lds(
                (const __attribute__((address_space(1))) void*)g1,
                (__attribute__((address_space(3))) void*)l1, 16, 0, 0);
            const unsigned short* g2 = Dtile + (size_t)row * K + k0 + sseg;
            unsigned short* l2 = Ds + c * 512 + lane * 8;
            __builtin_amdgcn_global_load_lds(
                (const __attribute__((address_space(1))) void*)g2,
                (__attribute__((address_space(3))) void*)l2, 16, 0, 0);
        }
        __syncthreads();   // drains vmcnt -> LDS tiles ready

        bf16x8 af[4], bfv[4];
#pragma unroll
        for (int i = 0; i < 4; ++i)
            af[i] = *(const bf16x8*)(Qs + (wrow + 16 * i + lm) * BK + pseg);
#pragma unroll
        for (int j = 0; j < 4; ++j)
            bfv[j] = *(const bf16x8*)(Ds + (wcol + 16 * j + lm) * BK + pseg);
#pragma unroll
        for (int i = 0; i < 4; ++i)
#pragma unroll
            for (int j = 0; j < 4; ++j)
                acc[i * 4 + j] = __builtin_amdgcn_mfma_f32_16x16x32_bf16(
                    af[i], bfv[j], acc[i * 4 + j], 0, 0, 0);
        __syncthreads();   // all waves done reading before next stage
    }

    // epilogue: exp, reduce across the 16 col-lanes, one atomic per row/quad.
    // C layout: col = lane&15, row = (lane>>4)*4 + reg  [m89/m91]
#pragma unroll
    for (int i = 0; i < 4; ++i)
#pragma unroll
        for (int r = 0; r < 4; ++r) {
            float e = 0.0f;
#pragma unroll
            for (int j = 0; j < 4; ++j)
                e += __expf(acc[i * 4 + j][r] * TEMP_INV);
            e += __shfl_xor(e, 1);
            e += __shfl_xor(e, 2);
            e += __shfl_xor(e, 4);
            e += __shfl_xor(e, 8);
            if (lm == 0)
                atomicAdd(&rowsum[qbase + wrow + 16 * i + 4 * lquad + r], e);
        }
}

// ---------------- final: loss = sum(log(rowsum) - pos)/B ----------------
__global__ void final_kernel(const float* __restrict__ rowsum,
                             const float* __restrict__ pos,
                             float* __restrict__ out, int B) {
    __shared__ float red[16];
    int tid = threadIdx.x;   // 1024 threads
    float s = 0.0f;
    for (int i = tid; i < B; i += blockDim.x)
        s += __logf(rowsum[i]) - pos[i];
    s += __shfl_xor(s, 32);
    s += __shfl_xor(s, 16);
    s += __shfl_xor(s, 8);
    s += __shfl_xor(s, 4);
    s += __shfl_xor(s, 2);
    s += __shfl_xor(s, 1);
    int w = tid >> 6, l = tid & 63;
    if (l == 0) red[w] = s;
    __syncthreads();
    if (tid == 0) {
        float t = 0.0f;
        int nw = blockDim.x >> 6;
        for (int i = 0; i < nw; ++i) t += red[i];
        out[0] = t / (float)B;
    }
}

extern "C" void kernel_launch(void* const* d_in, const int* in_sizes, int n_in,
                              void* d_out, int out_size, void* d_ws, size_t ws_size,
                              hipStream_t stream) {
    const float* Q   = (const float*)d_in[0];
    const float* Dm  = (const float*)d_in[1];
    const int* dper  = (const int*)d_in[2];
    float* out = (float*)d_out;

    const int DIM  = 1024;
    const int B    = in_sizes[0] / DIM;   // 4096
    const int Ntot = in_sizes[1] / DIM;   // 8192

    unsigned short* Qb = (unsigned short*)d_ws;
    unsigned short* Db = Qb + (size_t)B * DIM;
    float* rowsum = (float*)(Db + (size_t)Ntot * DIM);
    float* pos = rowsum + B;

    cvt_pos_kernel<<<B + Ntot, 256, 0, stream>>>(Q, Dm, dper, Qb, Db, rowsum,
                                                 pos, B, DIM);

    dim3 grid(B / BM, Ntot / BN);
    gemm_expsum_kernel<<<grid, 256, 0, stream>>>(Qb, Db, rowsum, DIM);

    final_kernel<<<1, 1024, 0, stream>>>(rowsum, pos, out, B);
}